// Round 7
// baseline (283.066 us; speedup 1.0000x reference)
//
#include <hip/hip_runtime.h>
#include <cstdint>

// DetNet NMS, round 25. r24 post-mortem: per-chunk cross-block handshake
// (consumer->worker->consumer round trip) = ~2.5us x 44 chunks = 110us.
// Unified law across r19/r21/r22/r23/r24: ANY per-chunk dependency that
// crosses a block (or sleeps) costs 1.4-2.5us x nc. Winning structure: the
// serial loop must be single-block, barrier-only, no polls on the chain.
// r25: diag-only masks (r23-proven builders, 64 parallel blocks, ~3us) +
// single-block consumer with register-owned boxes:
//   threads 64-511 own 19 boxes each (j = o*448 + (t-64), #pragma unroll ->
//   registers). Loop per chunk T, 3 barrier slots:
//     slot1: wave0 = A(T): ballot dead8, r23-verbatim band scan -> km
//            || waves1-7 = C-far: kept_{T-1} (LDS, dbl-buf) vs alive owned
//               j >= (T+1)*128; prune j < (T+1)*128.
//     slot2: owners publish kept of chunk T from REGISTERS -> nkb/nka/kr16
//            || wave0 prefetches band T+1 (doneD poll; builders far ahead).
//     slot3: C-near: owned j in chunk T+1 vs kept_T. wave0 idle.
//   Completeness: box j (chunk Cj) vs kept_T: T=Cj-1 by C-near(T); T<=Cj-2
//   by C-far at iter T+1<=Cj-1 (bound j>=(T+2)*128 <=> Cj>=T+2). All before
//   A(Cj). In-chunk order handled by the mask scan. QED.
// All decision-critical FP math __f*_rn in exact ref op order (suppressor/
// kept area first in union add, __fdiv_rn; r23-verified on HW, absmax 0.0).

#define M_TOT 8192
#define NMS_T 0.3f
#define MAGIC 0x5F3C9B71u
#define NOWN  19            // ceil(8192/448)

// ws layout (bytes)
#define WS_BOX   65536      // float4[8192] boxes_srt
#define WS_D     196608     // float[40960] d_srt
#define WS_VCNT  360448     // u32
#define WS_DONED 360512     // u32[64] per-chunk diag flags (MAGIC, no pre-zero)
#define WS_MDIAG 393216     // ulonglong2[8192] in-chunk diag mask (128 KB)

typedef unsigned long long u64t;

__device__ __forceinline__ uint32_t desc_key(float sv) {
    uint32_t u = __float_as_uint(sv);
    uint32_t m = (u & 0x80000000u) ? ~u : (u | 0x80000000u);
    return ~m;
}
__device__ __forceinline__ u64t rdl64(u64t v, int sl) {
    unsigned lo = (unsigned)__builtin_amdgcn_readlane((int)(unsigned)v, sl);
    unsigned hi = (unsigned)__builtin_amdgcn_readlane((int)(unsigned)(v >> 32), sl);
    return ((u64t)hi << 32) | lo;
}
__device__ __forceinline__ float area_of(float4 b) {
    return __fmul_rn(fmaxf(__fsub_rn(b.z, b.x), 0.0f),
                     fmaxf(__fsub_rn(b.w, b.y), 0.0f));
}

__device__ __forceinline__ void scatter_one(
    int i, int rank, u64t key,
    const float* __restrict__ det, const float* __restrict__ offsets,
    const float* __restrict__ scales,
    float4* __restrict__ boxes_srt, float* __restrict__ d_srt)
{
    uint32_t dkey = (uint32_t)(key >> 16);
    if (dkey >= 0x7FFFFFFFu) return;     // score <= 0: row stays zero
    int g = i >> 10;
    float d0 = __fadd_rn(offsets[g*5+0], __fmul_rn(det[i*5+0], scales[g*5+0]));
    float d1 = __fadd_rn(offsets[g*5+1], __fmul_rn(det[i*5+1], scales[g*5+1]));
    float d2 = __fadd_rn(offsets[g*5+2], __fmul_rn(det[i*5+2], scales[g*5+2]));
    float d3 = __fadd_rn(offsets[g*5+3], __fmul_rn(det[i*5+3], scales[g*5+3]));
    float d4 = __fadd_rn(offsets[g*5+4], __fmul_rn(det[i*5+4], scales[g*5+4]));
    d_srt[rank*5+0] = d0; d_srt[rank*5+1] = d1; d_srt[rank*5+2] = d2;
    d_srt[rank*5+3] = d3; d_srt[rank*5+4] = d4;
    float hw = __fmul_rn(d3, 0.5f), hh = __fmul_rn(d4, 0.5f);
    boxes_srt[rank] = make_float4(__fsub_rn(d1, hw), __fsub_rn(d2, hh),
                                  __fadd_rn(d1, hw), __fadd_rn(d2, hh));
}

// 128 blocks x 512 threads (r19/r23-proven, no ws zeroing needed)
__global__ __launch_bounds__(512) void k2_rank(
    const float* __restrict__ det, const float* __restrict__ offsets,
    const float* __restrict__ scales, const float* __restrict__ bounds,
    float4* __restrict__ boxes_srt, float* __restrict__ d_srt,
    unsigned int* __restrict__ vcnt, float* __restrict__ out)
{
    __shared__ u64t skey[M_TOT];
    __shared__ float soff[40], sscl[40], sbnd[32];
    __shared__ int sTop;
    int t = threadIdx.x;
    int lane = t & 63;
    if (t == 0) sTop = 0;
    if (t < 40) { soff[t] = offsets[t]; sscl[t] = scales[t]; }
    if (t < 32) { sbnd[t] = bounds[t]; }
    __syncthreads();

    #pragma unroll 4
    for (int s = 0; s < 16; ++s) {
        int u = s * 512 + t;
        int g = u >> 10;
        float raw_s = det[u * 5 + 0];
        float cx    = det[u * 5 + 1];
        float cy    = det[u * 5 + 2];
        float score = __fadd_rn(soff[g * 5 + 0], __fmul_rn(raw_s, sscl[g * 5 + 0]));
        bool valid = (cx < sbnd[g*4+1]) && (cx > sbnd[g*4+0]) &&
                     (cy < sbnd[g*4+3]) && (cy > sbnd[g*4+2]);
        float sv = valid ? score : -1.0f;
        uint32_t dk = desc_key(sv);
        bool push = dk < 0x7FFFFFFFu;
        u64t key = ((u64t)dk << 16) | (unsigned)u;
        u64t bal = __ballot(push);
        if (bal) {
            int lw = 0;
            if (lane == 0) lw = atomicAdd(&sTop, __popcll(bal));
            int wbase = __builtin_amdgcn_readfirstlane(lw);
            if (push) {
                int off = __popcll(bal & ((1ull << lane) - 1ull));
                skey[wbase + off] = key;
            }
        }
    }
    __syncthreads();
    int V = sTop;
    int Vpad = (V + 15) & ~15;
    if (t < Vpad - V) skey[V + t] = ~0ull;
    {
        int zb = blockIdx.x * 320;       // 128 blocks x 320 = 40960
        for (int z = zb + t; z < zb + 320; z += 512) out[z] = 0.0f;
    }
    __syncthreads();
    if (t == 0) *vcnt = (unsigned)V;

    int grp = t >> 3;                    // 0..63
    int jq  = t & 7;
    int i = blockIdx.x * 64 + grp;       // 128*64 = 8192
    int g = i >> 10;
    float raw_s = det[i * 5 + 0];
    float cx    = det[i * 5 + 1];
    float cy    = det[i * 5 + 2];
    float score = __fadd_rn(soff[g * 5 + 0], __fmul_rn(raw_s, sscl[g * 5 + 0]));
    bool valid = (cx < sbnd[g*4+1]) && (cx > sbnd[g*4+0]) &&
                 (cy < sbnd[g*4+3]) && (cy > sbnd[g*4+2]);
    float sv = valid ? score : -1.0f;
    uint32_t dk = desc_key(sv);
    u64t ki = ((u64t)dk << 16) | (unsigned)i;
    const ulonglong2* skey2 = (const ulonglong2*)skey;
    int c = 0;
    int nit = Vpad >> 4;
    #pragma unroll 4
    for (int it = 0; it < nit; ++it) {
        ulonglong2 kj = skey2[it * 8 + jq];
        c += (kj.x < ki) + (kj.y < ki);
    }
    c += __shfl_xor(c, 1);
    c += __shfl_xor(c, 2);
    c += __shfl_xor(c, 4);
    if (jq == 0)
        scatter_one(i, c, ki, det, offsets, scales, boxes_srt, d_srt);
}

// ---- diag builders (blocks 1..64) + single-block on-fly consumer ----
__global__ __launch_bounds__(512) void k34_diag(
    const float4* __restrict__ boxes_srt,
    const float* __restrict__ d_srt,
    const unsigned int* __restrict__ vcnt,
    ulonglong2* __restrict__ mdiag,
    unsigned int* __restrict__ doneD,
    float* __restrict__ out)
{
    int V = (int)*vcnt;
    int nc = (V + 127) >> 7;
    int t = threadIdx.x;

    if (blockIdx.x != 0) {
        // ---------------- builder: chunk c diag mask (r23-verbatim) -------
        int c = (int)blockIdx.x - 1;
        if (c >= nc) return;
        __shared__ float4 cbw[128];
        __shared__ float  caw[128];
        if (t < 128) {
            float4 b = boxes_srt[min(c * 128 + t, M_TOT - 1)];
            cbw[t] = b; caw[t] = area_of(b);
        }
        __syncthreads();
        int rl = t & 127, q = t >> 7;
        float4 bi = cbw[rl];
        float  ai = caw[rl];
        unsigned bits = 0u;
        int j0 = 32 * q;
        #pragma unroll 8
        for (int b = 0; b < 32; ++b) {
            int jl = j0 + b;
            float4 bj = cbw[jl];
            float  aj = caw[jl];
            float iw = fmaxf(__fsub_rn(fminf(bi.z, bj.z), fmaxf(bi.x, bj.x)), 0.0f);
            float ih = fmaxf(__fsub_rn(fminf(bi.w, bj.w), fmaxf(bi.y, bj.y)), 0.0f);
            float inter = __fmul_rn(iw, ih);
            float uni   = __fsub_rn(__fadd_rn(ai, aj), inter);
            float iou   = __fdiv_rn(inter, fmaxf(uni, 1e-9f));
            if (jl > rl && iou > NMS_T) bits |= 1u << b;
        }
        ((unsigned*)mdiag)[(c * 128 + rl) * 4 + q] = bits;
        __syncthreads();                 // all mdiag writes retired
        if (t == 0) {
            __threadfence();
            __hip_atomic_store(&doneD[c], MAGIC,
                               __ATOMIC_RELEASE, __HIP_MEMORY_SCOPE_AGENT);
        }
        return;
    }

    // ---------------- consumer (block 0) ----------------
    __shared__ unsigned char  dead8[M_TOT];     // 8 KB
    __shared__ unsigned short kr16[M_TOT];      // 16 KB kept sorted-rows
    __shared__ float4 nkb[2][128];              // new-kept boxes (dbl-buf)
    __shared__ float  nka[2][128];              // new-kept areas
    __shared__ u64t   sKm[2];
    __shared__ int    sNn[2];
    __shared__ int    sBase[2];
    __shared__ int    s_nk;

    for (int i = t; i < M_TOT; i += 512) dead8[i] = 0;
    if (t == 0) { s_nk = 0; sNn[0] = 0; sNn[1] = 0; }

    // register-owned boxes: threads 64..511 own j = o*448 + (t-64)
    int tw = t - 64;
    float4 bx[NOWN];
    float  ax[NOWN];
    unsigned alive = 0u;
    if (t >= 64) {
        #pragma unroll
        for (int o = 0; o < NOWN; ++o) {
            int j = o * 448 + tw;
            float4 b = boxes_srt[min(j, M_TOT - 1)];
            bx[o] = b;
            ax[o] = area_of(b);
            if (j < V) alive |= 1u << o;
        }
    }
    __syncthreads();
    if (nc <= 0) return;

    ulonglong2 bl, bh;                   // diag band, wave 0
    if (t < 64) {
        while (__hip_atomic_load(&doneD[0], __ATOMIC_RELAXED,
                                 __HIP_MEMORY_SCOPE_AGENT) != MAGIC)
            __builtin_amdgcn_s_sleep(2);
        (void)__hip_atomic_load(&doneD[0], __ATOMIC_ACQUIRE,
                                __HIP_MEMORY_SCOPE_AGENT);
        bl = mdiag[t];
        bh = mdiag[64 + t];
    }

    for (int T = 0; T < nc; ++T) {
        int par = T & 1;
        // ---- slot 1: A(T) on wave 0 || C-far(T-1) on waves 1-7 ----
        if (t < 64) {
            int lane = t;
            unsigned flo = dead8[T * 128 + lane];
            unsigned fhi = dead8[T * 128 + 64 + lane];
            u64t live_lo = ~__ballot(flo != 0u);
            u64t live_hi = ~__ballot(fhi != 0u);
            int rem = V - T * 128;
            if (rem < 128) {
                live_lo &= (rem >= 64) ? ~0ull : ((rem <= 0) ? 0ull : ((1ull << rem) - 1ull));
                int rh2 = rem - 64;
                live_hi &= (rh2 >= 64) ? ~0ull : ((rh2 <= 0) ? 0ull : ((1ull << rh2) - 1ull));
            }
            u64t km_lo = 0, km_hi = 0;
            while (live_lo) {
                int bs = (int)__builtin_ctzll(live_lo);
                km_lo |= 1ull << bs;
                u64t rml = rdl64(bl.x, bs);
                u64t rmh = rdl64(bl.y, bs);
                live_lo &= ~rml & ~(1ull << bs);
                live_hi &= ~rmh;
            }
            while (live_hi) {
                int bs = (int)__builtin_ctzll(live_hi);
                km_hi |= 1ull << bs;
                u64t rmh = rdl64(bh.y, bs);   // bh.x irrelevant: live_lo==0
                live_hi &= ~rmh & ~(1ull << bs);
            }
            if (lane == 0) {
                int nkm = __popcll(km_lo) + __popcll(km_hi);
                sKm[0] = km_lo; sKm[1] = km_hi;
                sBase[par] = s_nk;
                sNn[par] = nkm;
                s_nk += nkm;
            }
        } else {
            int np = sNn[par ^ 1];
            int fut0 = (T + 1) * 128;
            const float4* kb = nkb[par ^ 1];
            const float*  ka = nka[par ^ 1];
            #pragma unroll
            for (int o = 0; o < NOWN; ++o) {
                if (alive & (1u << o)) {
                    int j = o * 448 + tw;
                    if (j < fut0) {
                        alive &= ~(1u << o);      // past: prune forever
                    } else {
                        bool sup = false;
                        for (int k = 0; k < np; ++k) {
                            float4 bj = kb[k];
                            float  aj = ka[k];
                            float iw = fmaxf(__fsub_rn(fminf(bj.z, bx[o].z), fmaxf(bj.x, bx[o].x)), 0.0f);
                            float ih = fmaxf(__fsub_rn(fminf(bj.w, bx[o].w), fmaxf(bj.y, bx[o].y)), 0.0f);
                            float inter = __fmul_rn(iw, ih);
                            float uni   = __fsub_rn(__fadd_rn(aj, ax[o]), inter);
                            float iou   = __fdiv_rn(inter, fmaxf(uni, 1e-9f));
                            if (iou > NMS_T) { sup = true; break; }
                        }
                        if (sup) { alive &= ~(1u << o); dead8[j] = 1; }
                    }
                }
            }
        }
        __syncthreads();
        // ---- slot 2: owners publish kept of T || wave0 prefetch band T+1 --
        if (t >= 64) {
            u64t kmlo = sKm[0], kmhi = sKm[1];
            int base = sBase[par];
            int pl = __popcll(kmlo);
            #pragma unroll
            for (int o = 0; o < NOWN; ++o) {
                int j = o * 448 + tw;
                if ((j >> 7) == T) {
                    int l = j & 127;
                    bool kept = (l < 64) ? (((kmlo >> l) & 1ull) != 0ull)
                                         : (((kmhi >> (l - 64)) & 1ull) != 0ull);
                    if (kept) {
                        int pos = (l < 64)
                            ? __popcll(kmlo & ((1ull << l) - 1ull))
                            : pl + __popcll(kmhi & ((1ull << (l - 64)) - 1ull));
                        nkb[par][pos] = bx[o];
                        nka[par][pos] = ax[o];
                        kr16[base + pos] = (unsigned short)j;
                    }
                }
            }
        } else if (T + 1 < nc) {
            while (__hip_atomic_load(&doneD[T + 1], __ATOMIC_RELAXED,
                                     __HIP_MEMORY_SCOPE_AGENT) != MAGIC)
                __builtin_amdgcn_s_sleep(2);
            (void)__hip_atomic_load(&doneD[T + 1], __ATOMIC_ACQUIRE,
                                    __HIP_MEMORY_SCOPE_AGENT);
            bl = mdiag[(T + 1) * 128 + t];
            bh = mdiag[(T + 1) * 128 + 64 + t];
        }
        __syncthreads();
        // ---- slot 3: C-near: chunk T+1 vs kept_T ----
        if (t >= 64 && T + 1 < nc) {
            int np = sNn[par];
            const float4* kb = nkb[par];
            const float*  ka = nka[par];
            #pragma unroll
            for (int o = 0; o < NOWN; ++o) {
                if (alive & (1u << o)) {
                    int j = o * 448 + tw;
                    if ((j >> 7) == T + 1) {
                        bool sup = false;
                        for (int k = 0; k < np; ++k) {
                            float4 bj = kb[k];
                            float  aj = ka[k];
                            float iw = fmaxf(__fsub_rn(fminf(bj.z, bx[o].z), fmaxf(bj.x, bx[o].x)), 0.0f);
                            float ih = fmaxf(__fsub_rn(fminf(bj.w, bx[o].w), fmaxf(bj.y, bx[o].y)), 0.0f);
                            float inter = __fmul_rn(iw, ih);
                            float uni   = __fsub_rn(__fadd_rn(aj, ax[o]), inter);
                            float iou   = __fdiv_rn(inter, fmaxf(uni, 1e-9f));
                            if (iou > NMS_T) { sup = true; break; }
                        }
                        if (sup) { alive &= ~(1u << o); dead8[j] = 1; }
                    }
                }
            }
        }
        __syncthreads();
    }

    // ---- final: write kept output rows ----
    {
        int nk = s_nk;
        for (int idx = t; idx < nk; idx += 512) {
            int r = (int)kr16[idx];
            out[r * 5 + 0] = d_srt[r * 5 + 0];
            out[r * 5 + 1] = d_srt[r * 5 + 1];
            out[r * 5 + 2] = d_srt[r * 5 + 2];
            out[r * 5 + 3] = d_srt[r * 5 + 3];
            out[r * 5 + 4] = d_srt[r * 5 + 4];
        }
    }
}

extern "C" void kernel_launch(void* const* d_in, const int* in_sizes, int n_in,
                              void* d_out, int out_size, void* d_ws, size_t ws_size,
                              hipStream_t stream) {
    const float* det     = (const float*)d_in[0];
    const float* offsets = (const float*)d_in[1];
    const float* scales  = (const float*)d_in[2];
    const float* bounds  = (const float*)d_in[3];
    float* out = (float*)d_out;
    char* ws = (char*)d_ws;
    float4*       boxes = (float4*)(ws + WS_BOX);
    float*        d_srt = (float*)(ws + WS_D);
    unsigned int* vcnt  = (unsigned int*)(ws + WS_VCNT);
    unsigned int* doneD = (unsigned int*)(ws + WS_DONED);
    ulonglong2*   mdiag = (ulonglong2*)(ws + WS_MDIAG);

    k2_rank<<<128, 512, 0, stream>>>(det, offsets, scales, bounds, boxes, d_srt,
                                     vcnt, out);
    k34_diag<<<65, 512, 0, stream>>>(boxes, d_srt, vcnt, mdiag, doneD, out);
}

// Round 8
// 146.101 us; speedup vs baseline: 1.9375x; 1.9375x over previous
//
#include <hip/hip_runtime.h>
#include <cstdint>

// DetNet NMS, round 26. r25 post-mortem: on-fly suppression = V*kept/2
// IoUs ~ 18M VALU ops on ONE CU ~ 120us -> structurally dead. Laws:
//  (1) per-chunk cross-block/sleep handshakes: 1.4-2.5us x nc (r19/r21/r24);
//  (2) serial kept-row ORs on wave0: kept x 175cyc = +40us (r22);
//  (3) O(V*kept) IoU work must stay DISTRIBUTED -> full-mask build across
//      127 blocks (~20us) is right (r19).
// r26 = untried quadrant: distributed mask build (r19 verbatim) + single-
// block BARRIER-ONLY consumer:
//   LDS dead[128] (u64/word, V-tail baked). Per chunk T, 2 slots:
//   slot1: wave0: dead[2T..2T+1] broadcast-read, verified band scan -> km;
//          lane0 appends kept rows to kr16.
//   slot2: waves1-7: OR new-kept rows' mask words [2T+2,nwords) into dead[]
//          (lane owns words wbeg+l, wbeg+64+l; coalesced row reads; LDS
//          atomicOr; per-wave acquire of done[T] for cross-XCD visibility)
//          || wave0: poll done[T+1] (builders far ahead) + prefetch band.
//   No sleeps between waves; only __syncthreads. Dead-prop cost ~600cyc
//   overlapped vs r19's 1.4us handshake.
// All decision-critical FP math __f*_rn in exact ref op order (absmax 0.0
// r1-4, 6-9, 11-15, 17-25).

#define M_TOT 8192
#define NMS_T 0.3f

// ws layout (bytes)
#define WS_BOX   65536      // float4[8192]
#define WS_D     196608     // float[40960]
#define WS_VCNT  360448     // u32
#define WS_DONE  458752     // u32[64] per-chunk full-strip counters (zeroed by k2)
#define WS_MASK  524288     // u64[8192*128] = 8 MB

typedef unsigned long long u64t;

__device__ __forceinline__ uint32_t desc_key(float sv) {
    uint32_t u = __float_as_uint(sv);
    uint32_t m = (u & 0x80000000u) ? ~u : (u | 0x80000000u);
    return ~m;
}
__device__ __forceinline__ u64t rdl64(u64t v, int sl) {
    unsigned lo = (unsigned)__builtin_amdgcn_readlane((int)(unsigned)v, sl);
    unsigned hi = (unsigned)__builtin_amdgcn_readlane((int)(unsigned)(v >> 32), sl);
    return ((u64t)hi << 32) | lo;
}

__device__ __forceinline__ void scatter_one(
    int i, int rank, u64t key,
    const float* __restrict__ det, const float* __restrict__ offsets,
    const float* __restrict__ scales,
    float4* __restrict__ boxes_srt, float* __restrict__ d_srt)
{
    uint32_t dkey = (uint32_t)(key >> 16);
    if (dkey >= 0x7FFFFFFFu) return;     // score <= 0: row stays zero
    int g = i >> 10;
    float d0 = __fadd_rn(offsets[g*5+0], __fmul_rn(det[i*5+0], scales[g*5+0]));
    float d1 = __fadd_rn(offsets[g*5+1], __fmul_rn(det[i*5+1], scales[g*5+1]));
    float d2 = __fadd_rn(offsets[g*5+2], __fmul_rn(det[i*5+2], scales[g*5+2]));
    float d3 = __fadd_rn(offsets[g*5+3], __fmul_rn(det[i*5+3], scales[g*5+3]));
    float d4 = __fadd_rn(offsets[g*5+4], __fmul_rn(det[i*5+4], scales[g*5+4]));
    d_srt[rank*5+0] = d0; d_srt[rank*5+1] = d1; d_srt[rank*5+2] = d2;
    d_srt[rank*5+3] = d3; d_srt[rank*5+4] = d4;
    float hw = __fmul_rn(d3, 0.5f), hh = __fmul_rn(d4, 0.5f);
    boxes_srt[rank] = make_float4(__fsub_rn(d1, hw), __fsub_rn(d2, hh),
                                  __fadd_rn(d1, hw), __fadd_rn(d2, hh));
}

// 128 blocks x 512 threads (r19-proven)
__global__ __launch_bounds__(512) void k2_rank(
    const float* __restrict__ det, const float* __restrict__ offsets,
    const float* __restrict__ scales, const float* __restrict__ bounds,
    float4* __restrict__ boxes_srt, float* __restrict__ d_srt,
    unsigned int* __restrict__ vcnt, unsigned int* __restrict__ done,
    float* __restrict__ out)
{
    __shared__ u64t skey[M_TOT];
    __shared__ float soff[40], sscl[40], sbnd[32];
    __shared__ int sTop;
    int t = threadIdx.x;
    int lane = t & 63;
    if (t == 0) sTop = 0;
    if (t < 40) { soff[t] = offsets[t]; sscl[t] = scales[t]; }
    if (t < 32) { sbnd[t] = bounds[t]; }
    if (blockIdx.x == 0 && t < 64) done[t] = 0u;
    __syncthreads();

    #pragma unroll 4
    for (int s = 0; s < 16; ++s) {
        int u = s * 512 + t;
        int g = u >> 10;
        float raw_s = det[u * 5 + 0];
        float cx    = det[u * 5 + 1];
        float cy    = det[u * 5 + 2];
        float score = __fadd_rn(soff[g * 5 + 0], __fmul_rn(raw_s, sscl[g * 5 + 0]));
        bool valid = (cx < sbnd[g*4+1]) && (cx > sbnd[g*4+0]) &&
                     (cy < sbnd[g*4+3]) && (cy > sbnd[g*4+2]);
        float sv = valid ? score : -1.0f;
        uint32_t dk = desc_key(sv);
        bool push = dk < 0x7FFFFFFFu;
        u64t key = ((u64t)dk << 16) | (unsigned)u;
        u64t bal = __ballot(push);
        if (bal) {
            int lw = 0;
            if (lane == 0) lw = atomicAdd(&sTop, __popcll(bal));
            int wbase = __builtin_amdgcn_readfirstlane(lw);
            if (push) {
                int off = __popcll(bal & ((1ull << lane) - 1ull));
                skey[wbase + off] = key;
            }
        }
    }
    __syncthreads();
    int V = sTop;
    int Vpad = (V + 15) & ~15;
    if (t < Vpad - V) skey[V + t] = ~0ull;
    {
        int zb = blockIdx.x * 320;       // 128 blocks x 320 = 40960
        for (int z = zb + t; z < zb + 320; z += 512) out[z] = 0.0f;
    }
    __syncthreads();
    if (t == 0) *vcnt = (unsigned)V;

    int grp = t >> 3;                    // 0..63
    int jq  = t & 7;
    int i = blockIdx.x * 64 + grp;       // 128*64 = 8192
    int g = i >> 10;
    float raw_s = det[i * 5 + 0];
    float cx    = det[i * 5 + 1];
    float cy    = det[i * 5 + 2];
    float score = __fadd_rn(soff[g * 5 + 0], __fmul_rn(raw_s, sscl[g * 5 + 0]));
    bool valid = (cx < sbnd[g*4+1]) && (cx > sbnd[g*4+0]) &&
                 (cy < sbnd[g*4+3]) && (cy > sbnd[g*4+2]);
    float sv = valid ? score : -1.0f;
    uint32_t dk = desc_key(sv);
    u64t ki = ((u64t)dk << 16) | (unsigned)i;
    const ulonglong2* skey2 = (const ulonglong2*)skey;
    int c = 0;
    int nit = Vpad >> 4;
    #pragma unroll 4
    for (int it = 0; it < nit; ++it) {
        ulonglong2 kj = skey2[it * 8 + jq];
        c += (kj.x < ki) + (kj.y < ki);
    }
    c += __shfl_xor(c, 1);
    c += __shfl_xor(c, 2);
    c += __shfl_xor(c, 4);
    if (jq == 0)
        scatter_one(i, c, ki, det, offsets, scales, boxes_srt, d_srt);
}

// ---- fused: 127 builder blocks (r19 verbatim) + 1 barrier-only consumer ---
__global__ __launch_bounds__(512) void k34_bar(
    const float4* __restrict__ boxes_srt,
    const float* __restrict__ d_srt,
    const unsigned int* __restrict__ vcnt,
    u64t* __restrict__ mask,
    unsigned int* __restrict__ done,
    float* __restrict__ out)
{
    int V = (int)*vcnt;
    int nwords = (V + 63) >> 6;
    int nc = (V + 127) >> 7;             // 128-wide chunks
    int tid = threadIdx.x;

    if (blockIdx.x != 0) {
        // ---------------- builders (r19 chunk-major enumeration) ----------
        __shared__ float4 sb[8 * 65];
        __shared__ float  sa[8 * 65];
        int b = (int)blockIdx.x - 1;     // 0..126
        int gpre = 0;                    // global tile prefix
        for (int c = 0; c < nc; ++c) {
            int w0 = 2 * c;
            int Wc = nwords - w0;                  // >= 1 for c < nc
            int tiles = 2 * ((Wc + 7) >> 3);       // 2 row-halves x word-octets
            int tau0 = ((b - gpre) % 127 + 127) % 127;
            for (int tau = tau0; tau < tiles; tau += 127) {
                int rt = tau & 1, wt = tau >> 1;
                int rowbase = c * 128 + rt * 64;
                int wbase = w0 + wt * 8;
                {
                    int u = tid;
                    float4 bb = boxes_srt[min(wbase * 64 + u, M_TOT - 1)];
                    int cc = u >> 6, jj = u & 63;
                    sb[cc * 65 + jj] = bb;
                    sa[cc * 65 + jj] = __fmul_rn(fmaxf(__fsub_rn(bb.z, bb.x), 0.0f),
                                                 fmaxf(__fsub_rn(bb.w, bb.y), 0.0f));
                }
                __syncthreads();
                int r  = rowbase + (tid >> 3);
                int wl = tid & 7;
                int w  = wbase + wl;
                if (r < V && w < nwords) {
                    float4 bi = boxes_srt[r];
                    float ai = __fmul_rn(fmaxf(__fsub_rn(bi.z, bi.x), 0.0f),
                                         fmaxf(__fsub_rn(bi.w, bi.y), 0.0f));
                    u64t bits = 0;
                    #pragma unroll 4
                    for (int jj = 0; jj < 64; ++jj) {
                        float4 bj = sb[wl * 65 + jj];
                        float aj = sa[wl * 65 + jj];
                        float iw = fmaxf(__fsub_rn(fminf(bi.z, bj.z), fmaxf(bi.x, bj.x)), 0.0f);
                        float ih = fmaxf(__fsub_rn(fminf(bi.w, bj.w), fmaxf(bi.y, bj.y)), 0.0f);
                        float inter = __fmul_rn(iw, ih);
                        float uni   = __fsub_rn(__fadd_rn(ai, aj), inter);
                        float iou   = __fdiv_rn(inter, fmaxf(uni, 1e-9f));
                        int j = w * 64 + jj;
                        if (j > r && iou > NMS_T) bits |= 1ull << jj;
                    }
                    mask[(size_t)r * 128 + w] = bits;
                }
                __syncthreads();         // all tile writes retired
                if (tid == 0) {
                    int rows_t  = V - rowbase; if (rows_t > 64) rows_t = 64;
                    int words_t = nwords - wbase; if (words_t > 8) words_t = 8;
                    if (rows_t > 0) {
                        __threadfence();             // L2 writeback (agent)
                        __hip_atomic_fetch_add(&done[c], (unsigned)(rows_t * words_t),
                                               __ATOMIC_RELEASE, __HIP_MEMORY_SCOPE_AGENT);
                    }
                }
                __syncthreads();         // protect sb before next stage
            }
            gpre += tiles;
        }
        return;
    }

    // ---------------- consumer (block 0): barrier-only ----------------
    __shared__ u64t dead[128];
    __shared__ u64t km_s[2];
    __shared__ unsigned short kr16[M_TOT];
    __shared__ int s_nk;
    int lane = tid & 63;

    if (tid < 128) {
        int bw = tid * 64;
        u64t d0 = 0;
        if (bw >= V)           d0 = ~0ull;
        else if (bw + 64 > V)  d0 = (~0ull) << (V - bw);
        dead[tid] = d0;
    }
    if (tid == 0) s_nk = 0;
    __syncthreads();
    if (nc <= 0) return;

    ulonglong2 bl, bh;                   // diag band of chunk T (wave 0)
    if (tid < 64) {
        int rows_c = V; if (rows_c > 128) rows_c = 128;
        unsigned expc = (unsigned)(rows_c * nwords);
        while (__hip_atomic_load(&done[0], __ATOMIC_RELAXED, __HIP_MEMORY_SCOPE_AGENT) < expc)
            __builtin_amdgcn_s_sleep(2);
        (void)__hip_atomic_load(&done[0], __ATOMIC_ACQUIRE, __HIP_MEMORY_SCOPE_AGENT);
        bl = *(const ulonglong2*)(mask + (size_t)(lane) * 128);
        bh = *(const ulonglong2*)(mask + (size_t)(64 + lane) * 128);
    }

    for (int T = 0; T < nc; ++T) {
        // ---- slot 1: wave 0 scan ----
        if (tid < 64) {
            u64t live_lo = ~dead[2 * T];
            u64t live_hi = ~dead[2 * T + 1];
            u64t km_lo = 0, km_hi = 0;
            while (live_lo) {
                int bs = (int)__builtin_ctzll(live_lo);
                km_lo |= 1ull << bs;
                u64t rml = rdl64(bl.x, bs);
                u64t rmh = rdl64(bl.y, bs);
                live_lo &= ~rml & ~(1ull << bs);
                live_hi &= ~rmh;
            }
            while (live_hi) {
                int bs = (int)__builtin_ctzll(live_hi);
                km_hi |= 1ull << bs;
                u64t rmh = rdl64(bh.y, bs);   // bh.x irrelevant: live_lo==0
                live_hi &= ~rmh & ~(1ull << bs);
            }
            if (lane == 0) {
                km_s[0] = km_lo; km_s[1] = km_hi;
                int base = s_nk;
                u64t m = km_lo;
                while (m) {
                    int b_ = (int)__builtin_ctzll(m); m &= m - 1;
                    kr16[base++] = (unsigned short)(T * 128 + b_);
                }
                m = km_hi;
                while (m) {
                    int b_ = (int)__builtin_ctzll(m); m &= m - 1;
                    kr16[base++] = (unsigned short)(T * 128 + 64 + b_);
                }
                s_nk = base;
            }
        }
        __syncthreads();
        // ---- slot 2: waves 1-7 OR kept rows into dead || wave 0 prefetch --
        bool hn = (T + 1 < nc);
        if (tid >= 64) {
            int wbeg = 2 * T + 2;
            if (wbeg < nwords) {
                // cross-XCD visibility for this wave's mask reads
                (void)__hip_atomic_load(&done[T], __ATOMIC_ACQUIRE,
                                        __HIP_MEMORY_SCOPE_AGENT);
                u64t klo = km_s[0], khi = km_s[1];
                int wv = tid >> 6;           // 1..7
                int w1 = wbeg + lane;
                int w2 = wbeg + 64 + lane;
                bool v1 = w1 < nwords, v2 = w2 < nwords;
                int idx = 0;
                u64t m = klo;
                while (m) {
                    int b_ = (int)__builtin_ctzll(m); m &= m - 1;
                    if (idx % 7 == wv - 1) {
                        const u64t* rp = mask + (size_t)(T * 128 + b_) * 128;
                        if (v1) atomicOr(&dead[w1], rp[w1]);
                        if (v2) atomicOr(&dead[w2], rp[w2]);
                    }
                    ++idx;
                }
                m = khi;
                while (m) {
                    int b_ = (int)__builtin_ctzll(m); m &= m - 1;
                    if (idx % 7 == wv - 1) {
                        const u64t* rp = mask + (size_t)(T * 128 + 64 + b_) * 128;
                        if (v1) atomicOr(&dead[w1], rp[w1]);
                        if (v2) atomicOr(&dead[w2], rp[w2]);
                    }
                    ++idx;
                }
            }
        } else if (hn) {
            int c = T + 1;
            int rows_c = V - c * 128; if (rows_c > 128) rows_c = 128;
            unsigned expc = (unsigned)(rows_c * (nwords - 2 * c));
            while (__hip_atomic_load(&done[c], __ATOMIC_RELAXED, __HIP_MEMORY_SCOPE_AGENT) < expc)
                __builtin_amdgcn_s_sleep(2);
            (void)__hip_atomic_load(&done[c], __ATOMIC_ACQUIRE, __HIP_MEMORY_SCOPE_AGENT);
            bl = *(const ulonglong2*)(mask + (size_t)(c * 128 + lane) * 128 + 2 * c);
            bh = *(const ulonglong2*)(mask + (size_t)(c * 128 + 64 + lane) * 128 + 2 * c);
        }
        __syncthreads();
    }

    // ---- final: write kept output rows ----
    {
        int nk = s_nk;
        for (int idx = tid; idx < nk; idx += 512) {
            int r = (int)kr16[idx];
            out[r * 5 + 0] = d_srt[r * 5 + 0];
            out[r * 5 + 1] = d_srt[r * 5 + 1];
            out[r * 5 + 2] = d_srt[r * 5 + 2];
            out[r * 5 + 3] = d_srt[r * 5 + 3];
            out[r * 5 + 4] = d_srt[r * 5 + 4];
        }
    }
}

extern "C" void kernel_launch(void* const* d_in, const int* in_sizes, int n_in,
                              void* d_out, int out_size, void* d_ws, size_t ws_size,
                              hipStream_t stream) {
    const float* det     = (const float*)d_in[0];
    const float* offsets = (const float*)d_in[1];
    const float* scales  = (const float*)d_in[2];
    const float* bounds  = (const float*)d_in[3];
    float* out = (float*)d_out;
    char* ws = (char*)d_ws;
    float4*       boxes = (float4*)(ws + WS_BOX);
    float*        d_srt = (float*)(ws + WS_D);
    unsigned int* vcnt  = (unsigned int*)(ws + WS_VCNT);
    unsigned int* done  = (unsigned int*)(ws + WS_DONE);
    u64t*         mask  = (u64t*)(ws + WS_MASK);

    k2_rank<<<128, 512, 0, stream>>>(det, offsets, scales, bounds, boxes, d_srt,
                                     vcnt, done, out);
    k34_bar<<<128, 512, 0, stream>>>(boxes, d_srt, vcnt, mask, done, out);
}